// Round 7
// baseline (313.247 us; speedup 1.0000x reference)
//
#include <hip/hip_runtime.h>

// DIN attention unit, MI355X — round 7: 3 self-contained pass kernels.
// - prep/finalize kernels ELIMINATED: each block recomputes the query-fold
//   (W0 algebra) into LDS and derives scale/shift from the atomic sums
//   (kernel-boundary ordering). Kills 4 device-serializing tiny dispatches.
// - pass1 rebuilt on LDS-broadcast weights (R6's pinned-register weights got
//   parked in AGPRs -> v_accvgpr_read storm, 70 us at VALUBusy 19%).
// - pass2/3 j-loop software-pipelined: 10 ds_read_b128 issued at body top,
//   W1 consumed ~200 VALU cycles later; next-j wM row in flight across the
//   iteration. LDS broadcast (same addr all lanes) -> zero conflicts.
// mask input UNUSED (reference uses unmasked scores — reproduced bug).

#define BB 512
#define TT 2048
#define DD 20
#define C0 32
#define C1 16

#define NTH 256            // 4 waves/block
#define NPOS 4             // positions per thread in pass2/3
#define POSB (NTH * NPOS)  // 1024 positions per block (pass2/3)

// ws float offsets (atomic accumulators only)
#define WS_SUM0 0
#define WS_SQ0 32
#define WS_SUM1 64
#define WS_SQ1 80
#define EPS 1e-9f

#define PIN(x) asm volatile("" : "+v"(x))

__device__ __forceinline__ float fast_sigmoid(float x) {
    return __builtin_amdgcn_rcpf(1.0f + __expf(-x));
}

__device__ __forceinline__ void load_krow(const float* __restrict__ row,
                                          float* kk) {
    const float4* kr = (const float4*)row;  // rows are 80B => 16B aligned
    float4 a = kr[0], b = kr[1], c = kr[2], d = kr[3], e = kr[4];
    kk[0] = a.x; kk[1] = a.y; kk[2] = a.z; kk[3] = a.w;
    kk[4] = b.x; kk[5] = b.y; kk[6] = b.z; kk[7] = b.w;
    kk[8] = c.x; kk[9] = c.y; kk[10] = c.z; kk[11] = c.w;
    kk[12] = d.x; kk[13] = d.y; kk[14] = d.z; kk[15] = d.w;
    kk[16] = e.x; kk[17] = e.y; kk[18] = e.z; kk[19] = e.w;
}

// Compute the folded layer-1 weights for batch b directly into LDS.
// lw row j (24 floats): [0..19]=wM, [20]=c, [21]=sc0, [22]=sh0, [23]=al0.
// att=[q,k,q-k,q*k]@W0  ==  c_b + k·M_b ; M=W0_k-W0_d+diag(q)W0_p.
__device__ __forceinline__ void stage_fold(int b, int tid,
                                           const float* __restrict__ query,
                                           const float* __restrict__ W0,
                                           const float* __restrict__ b0,
                                           float* lw) {
    for (int idx = tid; idx < C0 * DD; idx += NTH) {
        int j = idx & 31, d = idx >> 5;
        float qd = query[b * DD + d];
        float w_k = W0[(DD + d) * C0 + j];
        float w_d = W0[(2 * DD + d) * C0 + j];
        float w_p = W0[(3 * DD + d) * C0 + j];
        lw[j * 24 + d] = w_k - w_d + qd * w_p;
    }
    if (tid < C0) {
        float cj = b0[tid];
        for (int d = 0; d < DD; ++d) {
            float qd = query[b * DD + d];
            cj = fmaf(qd, W0[d * C0 + tid] + W0[(2 * DD + d) * C0 + tid], cj);
        }
        lw[tid * 24 + 20] = cj;
    }
}

// ---------------- pass 1: layer-1 pre-activation stats ----------------
// Wave w handles channels [8w,8w+8); position-per-lane, 64/iter, key rows
// double-buffered; weights broadcast from LDS (6 b128 per channel).
__global__ __launch_bounds__(NTH, 2) void pass1_kernel(
    const float* __restrict__ keys, const float* __restrict__ query,
    const float* __restrict__ W0, const float* __restrict__ b0,
    float* __restrict__ ws) {
    const int b = blockIdx.x >> 2, chunk = blockIdx.x & 3;
    const int tid = threadIdx.x, wave = tid >> 6, lane = tid & 63;
    const int j0 = wave * 8;
    __shared__ float lw[C0 * 24];
    __shared__ float red[64];
    stage_fold(b, tid, query, W0, b0, lw);
    __syncthreads();

    const float* kbase = keys + ((size_t)b * TT + chunk * (TT / 4)) * DD;
    float kk[DD], kn[DD];
    load_krow(kbase + (size_t)lane * DD, kk);

    float s[8], q[8];
#pragma unroll
    for (int v = 0; v < 8; ++v) { s[v] = 0.f; q[v] = 0.f; }

#pragma unroll 1
    for (int it = 0; it < (TT / 4) / 64; ++it) {
        if (it < (TT / 4) / 64 - 1)
            load_krow(kbase + (size_t)((it + 1) * 64 + lane) * DD, kn);
#pragma unroll
        for (int d = 0; d < DD; ++d) PIN(kk[d]);

        const float4* wv = (const float4*)&lw[j0 * 24];
        float4 A = wv[0], B = wv[1], C2 = wv[2], D2 = wv[3], E2 = wv[4],
               F2 = wv[5];
#pragma unroll
        for (int jj = 0; jj < 8; ++jj) {
            float4 nA, nB, nC, nD, nE, nF;
            if (jj < 7) {
                const float4* nv = (const float4*)&lw[(j0 + jj + 1) * 24];
                nA = nv[0]; nB = nv[1]; nC = nv[2];
                nD = nv[3]; nE = nv[4]; nF = nv[5];
            }
            float wr[DD] = {A.x,  A.y,  A.z,  A.w,  B.x,  B.y,  B.z,
                            B.w,  C2.x, C2.y, C2.z, C2.w, D2.x, D2.y,
                            D2.z, D2.w, E2.x, E2.y, E2.z, E2.w};
            float h = F2.x;
#pragma unroll
            for (int d = 0; d < DD; ++d) h = fmaf(kk[d], wr[d], h);
            s[jj] += h;
            q[jj] = fmaf(h, h, q[jj]);
            if (jj < 7) {
                A = nA; B = nB; C2 = nC; D2 = nD; E2 = nE; F2 = nF;
            }
        }
#pragma unroll
        for (int d = 0; d < DD; ++d) kk[d] = kn[d];
    }
    float mine = 0.f;
#pragma unroll
    for (int v = 0; v < 16; ++v) {
        float val = (v < 8) ? s[v] : q[v - 8];
#pragma unroll
        for (int o = 32; o >= 1; o >>= 1) val += __shfl_xor(val, o);
        if (lane == v) mine = val;
    }
    if (lane < 16) {
        int j = j0 + (lane & 7);
        red[(lane < 8 ? 0 : 32) + j] = mine;
    }
    __syncthreads();
    if (tid < 64) atomicAdd(&ws[WS_SUM0 + tid], red[tid]);
}

// Derive dice0 scale/shift from the atomic sums into lw rows (per block).
__device__ __forceinline__ void stage_dice0(int tid,
                                            const float* __restrict__ ws,
                                            const float* __restrict__ a0,
                                            float* lw) {
    if (tid < C0) {
        const float invN = 1.0f / (float)(BB * TT);
        float mean = ws[WS_SUM0 + tid] * invN;
        float ex2 = ws[WS_SQ0 + tid] * invN;
        float sc = rsqrtf(ex2 - mean * mean + EPS);
        lw[tid * 24 + 21] = sc;
        lw[tid * 24 + 22] = -mean * sc;
        lw[tid * 24 + 23] = a0[tid];
    }
}

// Pipelined tower j-loop (shared by pass2/3). Consumes kk[NPOS][DD] (pinned),
// produces h1[NPOS][C1] (layer-2 preact minus b1). All weight reads are
// same-address broadcasts; W1 row consumed ~200 VALU cycles after issue.
#define TOWER_JLOOP()                                                        \
    float4 cA, cB, cC, cD, cE, cF;                                           \
    {                                                                        \
        const float4* wv = (const float4*)&lw[0];                            \
        cA = wv[0]; cB = wv[1]; cC = wv[2];                                  \
        cD = wv[3]; cE = wv[4]; cF = wv[5];                                  \
    }                                                                        \
    _Pragma("unroll 1") for (int j = 0; j < C0; ++j) {                       \
        const float4* uv = (const float4*)&lw1[j * C1];                      \
        float4 U0 = uv[0], U1 = uv[1], U2 = uv[2], U3 = uv[3];               \
        float4 nA, nB, nC, nD, nE, nF;                                       \
        if (j < C0 - 1) {                                                    \
            const float4* nv = (const float4*)&lw[(j + 1) * 24];             \
            nA = nv[0]; nB = nv[1]; nC = nv[2];                              \
            nD = nv[3]; nE = nv[4]; nF = nv[5];                              \
        }                                                                    \
        float wr[DD] = {cA.x, cA.y, cA.z, cA.w, cB.x, cB.y, cB.z,            \
                        cB.w, cC.x, cC.y, cC.z, cC.w, cD.x, cD.y,            \
                        cD.z, cD.w, cE.x, cE.y, cE.z, cE.w};                 \
        float h[NPOS];                                                       \
        _Pragma("unroll") for (int pp = 0; pp < NPOS; ++pp) {                \
            float hh = cF.x;                                                 \
            _Pragma("unroll") for (int d = 0; d < DD; ++d)                   \
                hh = fmaf(kk[pp][d], wr[d], hh);                             \
            h[pp] = hh;                                                      \
        }                                                                    \
        float ur[C1] = {U0.x, U0.y, U0.z, U0.w, U1.x, U1.y, U1.z, U1.w,      \
                        U2.x, U2.y, U2.z, U2.w, U3.x, U3.y, U3.z, U3.w};     \
        _Pragma("unroll") for (int pp = 0; pp < NPOS; ++pp) {                \
            float pr = fast_sigmoid(fmaf(h[pp], cF.y, cF.z));                \
            float h0d = h[pp] * (cF.w + pr * (1.0f - cF.w));                 \
            _Pragma("unroll") for (int c = 0; c < C1; ++c)                   \
                h1[pp][c] = fmaf(h0d, ur[c], h1[pp][c]);                     \
        }                                                                    \
        if (j < C0 - 1) {                                                    \
            cA = nA; cB = nB; cC = nC; cD = nD; cE = nE; cF = nF;            \
        }                                                                    \
    }

#define LOAD_AND_PIN_KEYS()                                                  \
    const float* kbase = keys + ((size_t)b * TT + chunk * POSB) * DD;        \
    float kk[NPOS][DD];                                                      \
    _Pragma("unroll") for (int pp = 0; pp < NPOS; ++pp)                      \
        load_krow(kbase + (size_t)(tid + pp * NTH) * DD, kk[pp]);            \
    _Pragma("unroll") for (int pp = 0; pp < NPOS; ++pp)                      \
        _Pragma("unroll") for (int d = 0; d < DD; ++d) PIN(kk[pp][d]);

// ---------------- pass 2: layer-2 pre-activation stats ----------------
__global__ __launch_bounds__(NTH, 2) void pass2_kernel(
    const float* __restrict__ keys, const float* __restrict__ query,
    const float* __restrict__ W0, const float* __restrict__ b0,
    const float* __restrict__ a0, const float* __restrict__ W1,
    const float* __restrict__ b1, float* __restrict__ ws) {
    const int b = blockIdx.x >> 1, chunk = blockIdx.x & 1;
    const int tid = threadIdx.x, wave = tid >> 6, lane = tid & 63;
    __shared__ float lw[C0 * 24];
    __shared__ float lw1[C0 * C1];
    __shared__ float red[4][32];
    stage_fold(b, tid, query, W0, b0, lw);
    stage_dice0(tid, ws, a0, lw);
    for (int idx = tid; idx < C0 * C1; idx += NTH) lw1[idx] = W1[idx];
    __syncthreads();

    LOAD_AND_PIN_KEYS()

    float h1[NPOS][C1];
#pragma unroll
    for (int pp = 0; pp < NPOS; ++pp)
#pragma unroll
        for (int c = 0; c < C1; ++c) h1[pp][c] = 0.f;

    TOWER_JLOOP()

    float s1[C1], q1[C1];
#pragma unroll
    for (int c = 0; c < C1; ++c) {
        float bc = b1[c], sv = 0.f, qv = 0.f;
#pragma unroll
        for (int pp = 0; pp < NPOS; ++pp) {
            float v = h1[pp][c] + bc;
            sv += v;
            qv = fmaf(v, v, qv);
        }
        s1[c] = sv;
        q1[c] = qv;
    }
    float mine = 0.f;
#pragma unroll
    for (int v = 0; v < 32; ++v) {
        float val = (v < C1) ? s1[v] : q1[v - C1];
#pragma unroll
        for (int o = 32; o >= 1; o >>= 1) val += __shfl_xor(val, o);
        if (lane == v) mine = val;
    }
    if (lane < 32) red[wave][lane] = mine;
    __syncthreads();
    if (tid < 32)
        atomicAdd(&ws[WS_SUM1 + tid],
                  red[0][tid] + red[1][tid] + red[2][tid] + red[3][tid]);
}

// ---------------- pass 3: full tower + weighted key-sum ----------------
__global__ __launch_bounds__(NTH, 2) void pass3_kernel(
    const float* __restrict__ keys, const float* __restrict__ query,
    const float* __restrict__ W0, const float* __restrict__ b0,
    const float* __restrict__ a0, const float* __restrict__ W1,
    const float* __restrict__ b1, const float* __restrict__ a1,
    const float* __restrict__ wk, const float* __restrict__ bk,
    const float* __restrict__ ws, float* __restrict__ out) {
    const int b = blockIdx.x >> 1, chunk = blockIdx.x & 1;
    const int tid = threadIdx.x, wave = tid >> 6, lane = tid & 63;
    __shared__ float lw[C0 * 24];
    __shared__ float lw1[C0 * C1];
    __shared__ float ld1[C1 * 4];  // sc1, sh1, al1, wk
    __shared__ float red[4][DD];
    stage_fold(b, tid, query, W0, b0, lw);
    stage_dice0(tid, ws, a0, lw);
    for (int idx = tid; idx < C0 * C1; idx += NTH) lw1[idx] = W1[idx];
    if (tid < C1) {
        const float invN = 1.0f / (float)(BB * TT);
        float mean = ws[WS_SUM1 + tid] * invN;
        float ex2 = ws[WS_SQ1 + tid] * invN;
        float sc = rsqrtf(ex2 - mean * mean + EPS);
        ld1[tid * 4 + 0] = sc;
        ld1[tid * 4 + 1] = -mean * sc;
        ld1[tid * 4 + 2] = a1[tid];
        ld1[tid * 4 + 3] = wk[tid];
    }
    __syncthreads();

    LOAD_AND_PIN_KEYS()

    float h1[NPOS][C1];
#pragma unroll
    for (int pp = 0; pp < NPOS; ++pp)
#pragma unroll
        for (int c = 0; c < C1; ++c) h1[pp][c] = 0.f;

    TOWER_JLOOP()

    const float bkv = bk[0];
    float oacc[DD];
#pragma unroll
    for (int d = 0; d < DD; ++d) oacc[d] = 0.f;
#pragma unroll
    for (int pp = 0; pp < NPOS; ++pp) {
        float score = bkv;
#pragma unroll
        for (int c = 0; c < C1; ++c) {
            float v = h1[pp][c] + b1[c];
            float pr = fast_sigmoid(fmaf(v, ld1[c * 4 + 0], ld1[c * 4 + 1]));
            float al = ld1[c * 4 + 2];
            float hd = v * (al + pr * (1.0f - al));
            score = fmaf(hd, ld1[c * 4 + 3], score);
        }
#pragma unroll
        for (int d = 0; d < DD; ++d) oacc[d] = fmaf(score, kk[pp][d], oacc[d]);
    }
    float mine = 0.f;
#pragma unroll
    for (int v = 0; v < DD; ++v) {
        float val = oacc[v];
#pragma unroll
        for (int o = 32; o >= 1; o >>= 1) val += __shfl_xor(val, o);
        if (lane == v) mine = val;
    }
    if (lane < DD) red[wave][lane] = mine;
    __syncthreads();
    if (tid < DD)
        atomicAdd(&out[b * DD + tid],
                  red[0][tid] + red[1][tid] + red[2][tid] + red[3][tid]);
}

extern "C" void kernel_launch(void* const* d_in, const int* in_sizes, int n_in,
                              void* d_out, int out_size, void* d_ws,
                              size_t ws_size, hipStream_t stream) {
    const float* keys = (const float*)d_in[0];
    const float* query = (const float*)d_in[1];
    // d_in[2] = mask: intentionally unused
    const float* W0 = (const float*)d_in[3];
    const float* b0 = (const float*)d_in[4];
    const float* a0 = (const float*)d_in[5];
    const float* W1 = (const float*)d_in[6];
    const float* b1 = (const float*)d_in[7];
    const float* a1 = (const float*)d_in[8];
    const float* wk = (const float*)d_in[9];
    const float* bk = (const float*)d_in[10];
    float* out = (float*)d_out;
    float* ws = (float*)d_ws;

    hipMemsetAsync(ws, 0, 96 * sizeof(float), stream);
    hipMemsetAsync(out, 0, (size_t)out_size * sizeof(float), stream);

    pass1_kernel<<<BB * 4, NTH, 0, stream>>>(keys, query, W0, b0, ws);
    pass2_kernel<<<BB * 2, NTH, 0, stream>>>(keys, query, W0, b0, a0, W1, b1,
                                             ws);
    pass3_kernel<<<BB * 2, NTH, 0, stream>>>(keys, query, W0, b0, a0, W1, b1,
                                             a1, wk, bk, ws, out);
}

// Round 8
// 298.534 us; speedup vs baseline: 1.0493x; 1.0493x over previous
//
#include <hip/hip_runtime.h>

// DIN attention unit, MI355X — round 8: weights on the SCALAR pipe.
// R7 diagnosis: pass1 was LDS-broadcast-bound (3.1M ds_read_b128 x 12cyc =
// 61us on the LDS pipe). Fix: folded weights in global memory (prep kernel),
// read via wave-uniform s_load (scalar pipe, K$-hot) inside j-loop-once
// structures. LDS carries only 4 dice params per channel (1 b128/j/wave).
// pass1 j-loop fully unrolled so s[32]/q[32] stay in registers.
// mask input UNUSED (reference uses unmasked scores — reproduced bug).

#define BB 512
#define TT 2048
#define DD 20
#define C0 32
#define C1 16

#define NTH 256
#define NPOS 4             // positions/thread in pass2/3
#define POSB (NTH * NPOS)  // 1024

// ws float offsets
#define WS_SUM0 0   // [0..31]  layer1 sum
#define WS_SQ0 32   // [32..63] layer1 sumsq
#define WS_SUM1 64  // [64..79] layer2 sum
#define WS_SQ1 80   // [80..95] layer2 sumsq
#define WS_BLOB 192
#define BLOB_J 24             // 20 wM + c + pad (96B, 32B-aligned rows)
#define BLOB_B (C0 * BLOB_J)  // 768 floats per batch
#define EPS 1e-9f

#define PIN(x) asm volatile("" : "+v"(x))

__device__ __forceinline__ float fast_sigmoid(float x) {
    return __builtin_amdgcn_rcpf(1.0f + __expf(-x));
}

__device__ __forceinline__ void load_krow(const float* __restrict__ row,
                                          float* kk) {
    const float4* kr = (const float4*)row;  // rows are 80B => 16B aligned
    float4 a = kr[0], b = kr[1], c = kr[2], d = kr[3], e = kr[4];
    kk[0] = a.x; kk[1] = a.y; kk[2] = a.z; kk[3] = a.w;
    kk[4] = b.x; kk[5] = b.y; kk[6] = b.z; kk[7] = b.w;
    kk[8] = c.x; kk[9] = c.y; kk[10] = c.z; kk[11] = c.w;
    kk[12] = d.x; kk[13] = d.y; kk[14] = d.z; kk[15] = d.w;
    kk[16] = e.x; kk[17] = e.y; kk[18] = e.z; kk[19] = e.w;
}

// ---------------- prep: fold query into layer-1 weights (global) --------
// att=[q,k,q-k,q*k]@W0+b0 == c_b + k·M_b ; M=W0_k-W0_d+diag(q)W0_p.
__global__ void prep_kernel(const float* __restrict__ query,
                            const float* __restrict__ W0,
                            const float* __restrict__ b0,
                            float* __restrict__ blob) {
    const int b = blockIdx.x * 2 + (threadIdx.x >> 5);
    const int j = threadIdx.x & 31;
    float cj = b0[j];
    float* dst = blob + (size_t)b * BLOB_B + j * BLOB_J;
#pragma unroll
    for (int d = 0; d < DD; ++d) {
        float w_q = W0[d * C0 + j];
        float w_k = W0[(DD + d) * C0 + j];
        float w_d = W0[(2 * DD + d) * C0 + j];
        float w_p = W0[(3 * DD + d) * C0 + j];
        float qd = query[b * DD + d];
        dst[d] = w_k - w_d + qd * w_p;
        cj = fmaf(qd, w_q + w_d, cj);
    }
    dst[20] = cj;
}

// ---------------- pass 1: layer-1 pre-activation stats ----------------
// Thread owns 2 positions; j-loop FULLY UNROLLED (s/q register-indexed);
// weights via wave-uniform s_load. Zero LDS in the main loop.
__global__ __launch_bounds__(NTH, 2) void pass1_kernel(
    const float* __restrict__ keys, const float* __restrict__ blob,
    float* __restrict__ ws) {
    const int b = blockIdx.x >> 2, chunk = blockIdx.x & 3;
    const int tid = threadIdx.x, wave = tid >> 6, lane = tid & 63;
    const float* kbase = keys + ((size_t)b * TT + chunk * (TT / 4)) * DD;
    const float* wb = blob + (size_t)b * BLOB_B;

    float kk[2][DD];
    load_krow(kbase + (size_t)tid * DD, kk[0]);
    load_krow(kbase + (size_t)(tid + NTH) * DD, kk[1]);
#pragma unroll
    for (int pp = 0; pp < 2; ++pp)
#pragma unroll
        for (int d = 0; d < DD; ++d) PIN(kk[pp][d]);

    float s[C0], q[C0];
#pragma unroll
    for (int j = 0; j < C0; ++j) { s[j] = 0.f; q[j] = 0.f; }

#pragma unroll
    for (int j = 0; j < C0; ++j) {
        const float* w = wb + j * BLOB_J;  // uniform -> s_load
        float h0 = w[20], h1v = w[20];
#pragma unroll
        for (int d = 0; d < DD; ++d) {
            h0 = fmaf(kk[0][d], w[d], h0);
            h1v = fmaf(kk[1][d], w[d], h1v);
        }
        s[j] += h0 + h1v;
        q[j] = fmaf(h0, h0, q[j]);
        q[j] = fmaf(h1v, h1v, q[j]);
    }
    // butterfly: lane v ends with total of value v (v<32: s, else q)
    float mine = 0.f;
#pragma unroll
    for (int v = 0; v < 64; ++v) {
        float val = (v < C0) ? s[v] : q[v - C0];
#pragma unroll
        for (int o = 32; o >= 1; o >>= 1) val += __shfl_xor(val, o);
        if (lane == v) mine = val;
    }
    __shared__ float red[4][64];
    red[wave][lane] = mine;
    __syncthreads();
    if (tid < 64)
        atomicAdd(&ws[tid],
                  red[0][tid] + red[1][tid] + red[2][tid] + red[3][tid]);
}

// Load NPOS key rows and PIN them (defeat rematerialization).
#define LOAD_AND_PIN_KEYS()                                                  \
    const float* kbase = keys + ((size_t)b * TT + chunk * POSB) * DD;        \
    float kk[NPOS][DD];                                                      \
    _Pragma("unroll") for (int pp = 0; pp < NPOS; ++pp)                      \
        load_krow(kbase + (size_t)(tid + pp * NTH) * DD, kk[pp]);            \
    _Pragma("unroll") for (int pp = 0; pp < NPOS; ++pp)                      \
        _Pragma("unroll") for (int d = 0; d < DD; ++d) PIN(kk[pp][d]);

// j-loop: wM via s_load, W1 row via s_load, dice params via one broadcast
// ds_read_b128. Produces h1[NPOS][C1] (layer-2 preact minus b1).
#define TOWER_JLOOP()                                                        \
    _Pragma("unroll 2") for (int j = 0; j < C0; ++j) {                       \
        float4 P = ld0[j]; /* {c, sc0, sh0, al0} broadcast b128 */           \
        const float* w = wb + j * BLOB_J; /* uniform -> s_load */            \
        const float* u = W1 + j * C1;     /* uniform -> s_load */            \
        float h[NPOS];                                                       \
        _Pragma("unroll") for (int pp = 0; pp < NPOS; ++pp) {                \
            float hh = P.x;                                                  \
            _Pragma("unroll") for (int d = 0; d < DD; ++d)                   \
                hh = fmaf(kk[pp][d], w[d], hh);                              \
            h[pp] = hh;                                                      \
        }                                                                    \
        _Pragma("unroll") for (int pp = 0; pp < NPOS; ++pp) {                \
            float pr = fast_sigmoid(fmaf(h[pp], P.y, P.z));                  \
            float h0d = h[pp] * (P.w + pr * (1.0f - P.w));                   \
            _Pragma("unroll") for (int c = 0; c < C1; ++c)                   \
                h1[pp][c] = fmaf(h0d, u[c], h1[pp][c]);                      \
        }                                                                    \
    }

// Stage {c, sc0, sh0, al0} per layer-1 channel into LDS (from atomic sums).
#define STAGE_DICE0()                                                        \
    if (tid < C0) {                                                          \
        const float invN = 1.0f / (float)(BB * TT);                          \
        float mean = ws[WS_SUM0 + tid] * invN;                               \
        float ex2 = ws[WS_SQ0 + tid] * invN;                                 \
        float sc = rsqrtf(ex2 - mean * mean + EPS);                          \
        ld0[tid] = make_float4(blob[(size_t)b * BLOB_B + tid * BLOB_J + 20], \
                               sc, -mean * sc, a0[tid]);                     \
    }

// ---------------- pass 2: layer-2 pre-activation stats ----------------
__global__ __launch_bounds__(NTH, 2) void pass2_kernel(
    const float* __restrict__ keys, const float* __restrict__ blob,
    const float* __restrict__ a0, const float* __restrict__ W1,
    const float* __restrict__ b1, float* __restrict__ ws) {
    const int b = blockIdx.x >> 1, chunk = blockIdx.x & 1;
    const int tid = threadIdx.x, wave = tid >> 6, lane = tid & 63;
    const float* wb = blob + (size_t)b * BLOB_B;
    __shared__ float4 ld0[C0];
    __shared__ float red[4][32];
    STAGE_DICE0()
    __syncthreads();

    LOAD_AND_PIN_KEYS()

    float h1[NPOS][C1];
#pragma unroll
    for (int pp = 0; pp < NPOS; ++pp)
#pragma unroll
        for (int c = 0; c < C1; ++c) h1[pp][c] = 0.f;

    TOWER_JLOOP()

    float s1[C1], q1[C1];
#pragma unroll
    for (int c = 0; c < C1; ++c) {
        float bc = b1[c], sv = 0.f, qv = 0.f;
#pragma unroll
        for (int pp = 0; pp < NPOS; ++pp) {
            float v = h1[pp][c] + bc;
            sv += v;
            qv = fmaf(v, v, qv);
        }
        s1[c] = sv;
        q1[c] = qv;
    }
    float mine = 0.f;
#pragma unroll
    for (int v = 0; v < 32; ++v) {
        float val = (v < C1) ? s1[v] : q1[v - C1];
#pragma unroll
        for (int o = 32; o >= 1; o >>= 1) val += __shfl_xor(val, o);
        if (lane == v) mine = val;
    }
    if (lane < 32) red[wave][lane] = mine;
    __syncthreads();
    if (tid < 32)
        atomicAdd(&ws[WS_SUM1 + tid],
                  red[0][tid] + red[1][tid] + red[2][tid] + red[3][tid]);
}

// ---------------- pass 3: full tower + weighted key-sum ----------------
__global__ __launch_bounds__(NTH, 2) void pass3_kernel(
    const float* __restrict__ keys, const float* __restrict__ blob,
    const float* __restrict__ a0, const float* __restrict__ W1,
    const float* __restrict__ b1, const float* __restrict__ a1,
    const float* __restrict__ wk, const float* __restrict__ bk,
    const float* __restrict__ ws, float* __restrict__ out) {
    const int b = blockIdx.x >> 1, chunk = blockIdx.x & 1;
    const int tid = threadIdx.x, wave = tid >> 6, lane = tid & 63;
    const float* wb = blob + (size_t)b * BLOB_B;
    __shared__ float4 ld0[C0];
    __shared__ float4 ld1[C1];  // {sc1, sh1, al1, wk}
    __shared__ float red[4][DD];
    STAGE_DICE0()
    if (tid < C1) {
        const float invN = 1.0f / (float)(BB * TT);
        float mean = ws[WS_SUM1 + tid] * invN;
        float ex2 = ws[WS_SQ1 + tid] * invN;
        float sc = rsqrtf(ex2 - mean * mean + EPS);
        ld1[tid] = make_float4(sc, -mean * sc, a1[tid], wk[tid]);
    }
    __syncthreads();

    LOAD_AND_PIN_KEYS()

    float h1[NPOS][C1];
#pragma unroll
    for (int pp = 0; pp < NPOS; ++pp)
#pragma unroll
        for (int c = 0; c < C1; ++c) h1[pp][c] = 0.f;

    TOWER_JLOOP()

    const float bkv = bk[0];
    float oacc[DD];
#pragma unroll
    for (int d = 0; d < DD; ++d) oacc[d] = 0.f;
#pragma unroll
    for (int pp = 0; pp < NPOS; ++pp) {
        float score = bkv;
#pragma unroll
        for (int c = 0; c < C1; ++c) {
            float v = h1[pp][c] + b1[c];
            float4 Q = ld1[c];
            float pr = fast_sigmoid(fmaf(v, Q.x, Q.y));
            float hd = v * (Q.z + pr * (1.0f - Q.z));
            score = fmaf(hd, Q.w, score);
        }
#pragma unroll
        for (int d = 0; d < DD; ++d) oacc[d] = fmaf(score, kk[pp][d], oacc[d]);
    }
    float mine = 0.f;
#pragma unroll
    for (int v = 0; v < DD; ++v) {
        float val = oacc[v];
#pragma unroll
        for (int o = 32; o >= 1; o >>= 1) val += __shfl_xor(val, o);
        if (lane == v) mine = val;
    }
    if (lane < DD) red[wave][lane] = mine;
    __syncthreads();
    if (tid < DD)
        atomicAdd(&out[b * DD + tid],
                  red[0][tid] + red[1][tid] + red[2][tid] + red[3][tid]);
}

extern "C" void kernel_launch(void* const* d_in, const int* in_sizes, int n_in,
                              void* d_out, int out_size, void* d_ws,
                              size_t ws_size, hipStream_t stream) {
    const float* keys = (const float*)d_in[0];
    const float* query = (const float*)d_in[1];
    // d_in[2] = mask: intentionally unused
    const float* W0 = (const float*)d_in[3];
    const float* b0 = (const float*)d_in[4];
    const float* a0 = (const float*)d_in[5];
    const float* W1 = (const float*)d_in[6];
    const float* b1 = (const float*)d_in[7];
    const float* a1 = (const float*)d_in[8];
    const float* wk = (const float*)d_in[9];
    const float* bk = (const float*)d_in[10];
    float* out = (float*)d_out;
    float* ws = (float*)d_ws;
    float* blob = ws + WS_BLOB;  // 512*768 floats = 1.5 MB scratch

    hipMemsetAsync(ws, 0, 96 * sizeof(float), stream);
    hipMemsetAsync(out, 0, (size_t)out_size * sizeof(float), stream);

    prep_kernel<<<BB / 2, 64, 0, stream>>>(query, W0, b0, blob);

    pass1_kernel<<<BB * 4, NTH, 0, stream>>>(keys, blob, ws);
    pass2_kernel<<<BB * 2, NTH, 0, stream>>>(keys, blob, a0, W1, b1, ws);
    pass3_kernel<<<BB * 2, NTH, 0, stream>>>(keys, blob, a0, W1, b1, a1, wk,
                                             bk, ws, out);
}